// Round 3
// baseline (403.995 us; speedup 1.0000x reference)
//
#include <hip/hip_runtime.h>
#include <cstdint>
#include <cstddef>

// Problem constants (Learnable_32650341384420)
#define HH 1024      // H (channels)
#define LL 8192      // L (sequence)
#define NB 4         // B (batch)
#define KD 64
#define KLEN 512     // KD * 2^(NS-1)

typedef float v4f  __attribute__((ext_vector_type(4)));
typedef float v16f __attribute__((ext_vector_type(16)));
typedef short v8s  __attribute__((ext_vector_type(8)));

__device__ __forceinline__ unsigned short f2bf(float f) {
  union { float f; unsigned int u; } x; x.f = f;
  unsigned int r = x.u + 0x7fffu + ((x.u >> 16) & 1u);
  return (unsigned short)(r >> 16);
}
__device__ __forceinline__ float bf2f(unsigned int s) {
  union { unsigned int u; float f; } x; x.u = s << 16; return x.f;
}

// XOR swizzle on 16B units: kills the 16-way bank conflict of lane-stride-64B
// b128 reads while preserving alignment (low 3 short-indices untouched).
// Property: swz(L + 1024) == swz(L) + 1024 (unit +128 doesn't change low bits).
__device__ __forceinline__ int swz(int L) {
  int u = L >> 3;
  return ((u ^ ((u >> 2) & 7)) << 3) | (L & 7);
}

// ---------------------------------------------------------------------------
// K1: build normalized 512-tap kernel per h (fp32).
// ---------------------------------------------------------------------------
__global__ __launch_bounds__(512) void build_k_kernel(
    const float* __restrict__ k0, const float* __restrict__ k1,
    const float* __restrict__ k2, const float* __restrict__ k3,
    float* __restrict__ kout) {
  __shared__ float lk[4][KD];
  __shared__ float red[512];
  const int h = blockIdx.x;
  const int t = threadIdx.x;
  if (t < 256) {
    int i = t >> 6, j = t & 63;
    const float* src = (i == 0) ? k0 : (i == 1) ? k1 : (i == 2) ? k2 : k3;
    lk[i][j] = src[h * KD + j];
  }
  __syncthreads();
  float kt = 0.f;
#pragma unroll
  for (int i = 0; i < 4; i++) {
    int len = KD << i;
    if (t < len) {
      float inv = 1.0f / (float)(1 << i);
      float c = ((float)t + 0.5f) * inv - 0.5f;
      c = fminf(fmaxf(c, 0.0f), 63.0f);
      int lo = (int)floorf(c);
      int hi = min(lo + 1, 63);
      float w = c - (float)lo;
      float v = lk[i][lo] * (1.0f - w) + lk[i][hi] * w;
      kt += v * (float)(1 << (3 - i));
    }
  }
  red[t] = kt * kt;
  __syncthreads();
  for (int s = 256; s > 0; s >>= 1) {
    if (t < s) red[t] += red[t + s];
    __syncthreads();
  }
  float norm = sqrtf(red[0]);
  kout[h * KLEN + t] = kt / norm;
}

// ---------------------------------------------------------------------------
// K2: W (fp32) -> bf16 bits
// ---------------------------------------------------------------------------
__global__ void w2bf_kernel(const float* __restrict__ W,
                            unsigned short* __restrict__ Wb, int n) {
  int i = blockIdx.x * blockDim.x + threadIdx.x;
  if (i < n) Wb[i] = f2bf(W[i]);
}

// ---------------------------------------------------------------------------
// K3 v3: depthwise causal 512-tap FIR via block-Toeplitz MFMA.
// One block per (h, batch-pair). su XOR-swizzled (conflict-free b128 reads).
// Epilogue reads u from LDS (bf16) instead of global.
// ---------------------------------------------------------------------------
__global__ __launch_bounds__(256) void conv_kernel(
    const float* __restrict__ u, const float* __restrict__ kk,
    const float* __restrict__ D, unsigned short* __restrict__ g) {
  __shared__ __align__(16) unsigned short Apk[34 * 512];  // fragment-packed A
  __shared__ __align__(16) unsigned short su[512 + LL];   // bf16 u row (swizzled)
  __shared__ __align__(16) float skk[KLEN];               // fp32 k row

  const int h = blockIdx.x >> 1;
  const int bp = (blockIdx.x & 1) * 2;  // batch pair {bp, bp+1}
  const int tid = threadIdx.x;
  const int w = tid >> 6;
  const int ln = tid & 63;
  const int n = ln & 31;        // MFMA col (l-block index)
  const int q = ln >> 5;        // k-half selector

  // stage normalized kernel row
  if (tid < 128) *(float4*)(skk + tid * 4) = *(const float4*)(kk + (size_t)h * KLEN + tid * 4);
  __syncthreads();

  // build fragment-packed Toeplitz A: Apk[s*512 + lane*8 + j] = A[m][16s+q*8+j]
  // m=lane&31, q2=lane>>5; a=s>>1; c=(s&1)*16+q2*8+j; t=32a+m-c
#pragma unroll 4
  for (int e = 0; e < 68; ++e) {
    int idx = e * 256 + tid;
    int s = idx >> 9;
    int lane = (idx >> 3) & 63;
    int j = idx & 7;
    int m = lane & 31, q2 = lane >> 5;
    int c = ((s & 1) << 4) + (q2 << 3) + j;
    int t = ((s >> 1) << 5) + m - c;
    Apk[idx] = (t >= 0 && t < KLEN) ? f2bf(skk[t]) : (unsigned short)0;
  }

  const float Dh = D[h];
  const int XB = (w * 64 + n) << 5;  // 32*(w*64+n): tile0 base l

  for (int bi = 0; bi < 2; ++bi) {
    const int b = bp + bi;
    __syncthreads();  // prev-iter su readers done (and Apk built, iter 0)
    const float* __restrict__ urow = u + ((size_t)b * HH + h) * LL;
    // zero left pad (512 elems): 128 threads x uint2
    if (tid < 128) {
      uint2 z; z.x = 0; z.y = 0;
      *(uint2*)(su + swz(tid * 4)) = z;
    }
    // stage u row -> bf16 (swizzled)
#pragma unroll
    for (int r = 0; r < 8; ++r) {
      int i = r * 1024 + tid * 4;
      float4 v = *(const float4*)(urow + i);
      uint2 p;
      p.x = (unsigned)f2bf(v.x) | ((unsigned)f2bf(v.y) << 16);
      p.y = (unsigned)f2bf(v.z) | ((unsigned)f2bf(v.w) << 16);
      *(uint2*)(su + swz(512 + i)) = p;
    }
    __syncthreads();

    v16f acc0, acc1;
#pragma unroll
    for (int r = 0; r < 16; ++r) { acc0[r] = 0.f; acc1[r] = 0.f; }

#pragma unroll
    for (int s = 0; s < 34; ++s) {
      const int off = ((s & 1) << 4) - ((s >> 1) << 5);
      v8s af = *(const v8s*)(Apk + (s << 9) + (ln << 3));
      const int p0 = swz(512 + XB + (q << 3) + off);
      v8s b0 = *(const v8s*)(su + p0);
      v8s b1 = *(const v8s*)(su + p0 + 1024);  // swz(L+1024)=swz(L)+1024
      acc0 = __builtin_amdgcn_mfma_f32_32x32x16_bf16(af, b0, acc0, 0, 0, 0);
      acc1 = __builtin_amdgcn_mfma_f32_32x32x16_bf16(af, b1, acc1, 0, 0, 0);
    }

    // epilogue: C layout col=n, row=(reg&3)+8*(reg>>2)+4*q; u from LDS (bf16)
    unsigned short* grow = g + ((size_t)b * HH + h) * LL;
#pragma unroll
    for (int t = 0; t < 2; ++t) {
      const int i0 = w * 64 + t * 32;
#pragma unroll
      for (int rg = 0; rg < 4; ++rg) {
        const int l = 32 * (i0 + n) + 8 * rg + 4 * q;
        uint2 uu = *(const uint2*)(su + swz(512 + l));
        float up[4];
        up[0] = bf2f(uu.x & 0xffffu); up[1] = bf2f(uu.x >> 16);
        up[2] = bf2f(uu.y & 0xffffu); up[3] = bf2f(uu.y >> 16);
        unsigned short hb[4];
#pragma unroll
        for (int rr = 0; rr < 4; ++rr) {
          float y = (t ? acc1[rg * 4 + rr] : acc0[rg * 4 + rr]) + Dh * up[rr];
          float ge = 0.5f * y * (1.0f + erff(y * 0.70710678118654752f));
          hb[rr] = f2bf(ge);
        }
        uint2 p;
        p.x = (unsigned)hb[0] | ((unsigned)hb[1] << 16);
        p.y = (unsigned)hb[2] | ((unsigned)hb[3] << 16);
        *(uint2*)(grow + l) = p;
      }
    }
  }
}

// ---------------------------------------------------------------------------
// K4: transpose g[b][h][l] -> g_t[b][l][h] (bf16), 64x64 LDS tiles
// ---------------------------------------------------------------------------
__global__ __launch_bounds__(256) void transpose_kernel(
    const unsigned short* __restrict__ g, unsigned short* __restrict__ gt) {
  __shared__ unsigned short s[64][65];
  const int bid = blockIdx.x;
  const int lc = bid & 127;
  const int hc = (bid >> 7) & 15;
  const int b = bid >> 11;
  const int l0 = lc * 64, h0 = hc * 64;
  const int tid = threadIdx.x;
  const int seg = tid & 7, rr = tid >> 3;
#pragma unroll
  for (int p = 0; p < 2; p++) {
    int r = p * 32 + rr;
    uint4 v = *(const uint4*)(g + (size_t)(b * HH + h0 + r) * LL + l0 + seg * 8);
    s[r][seg * 8 + 0] = (unsigned short)(v.x);
    s[r][seg * 8 + 1] = (unsigned short)(v.x >> 16);
    s[r][seg * 8 + 2] = (unsigned short)(v.y);
    s[r][seg * 8 + 3] = (unsigned short)(v.y >> 16);
    s[r][seg * 8 + 4] = (unsigned short)(v.z);
    s[r][seg * 8 + 5] = (unsigned short)(v.z >> 16);
    s[r][seg * 8 + 6] = (unsigned short)(v.w);
    s[r][seg * 8 + 7] = (unsigned short)(v.w >> 16);
  }
  __syncthreads();
#pragma unroll
  for (int p = 0; p < 2; p++) {
    int lr = p * 32 + rr;
    unsigned int a0 = (unsigned)s[seg * 8 + 0][lr] | ((unsigned)s[seg * 8 + 1][lr] << 16);
    unsigned int a1 = (unsigned)s[seg * 8 + 2][lr] | ((unsigned)s[seg * 8 + 3][lr] << 16);
    unsigned int a2 = (unsigned)s[seg * 8 + 4][lr] | ((unsigned)s[seg * 8 + 5][lr] << 16);
    unsigned int a3 = (unsigned)s[seg * 8 + 6][lr] | ((unsigned)s[seg * 8 + 7][lr] << 16);
    uint4 ov; ov.x = a0; ov.y = a1; ov.z = a2; ov.w = a3;
    *(uint4*)(gt + (size_t)(b * LL + l0 + lr) * HH + h0 + seg * 8) = ov;
  }
}

// ---------------------------------------------------------------------------
// K5: GEMM out[b][o][l] = sum_h W[o][h] * g_t[b*L+l][h] + bias[o]
// ---------------------------------------------------------------------------
__device__ __forceinline__ void gll16(const void* g, void* l) {
  __builtin_amdgcn_global_load_lds(
      (const __attribute__((address_space(1))) unsigned int*)g,
      (__attribute__((address_space(3))) unsigned int*)l, 16, 0, 0);
}

__global__ __launch_bounds__(256) void gemm_kernel(
    const unsigned short* __restrict__ A,   // W bf16 [1024][1024]
    const unsigned short* __restrict__ Bt,  // g_t bf16 [32768][1024]
    const float* __restrict__ bias, float* __restrict__ out) {
  __shared__ __align__(16) unsigned short sA[128 * 32];
  __shared__ __align__(16) unsigned short sB[128 * 32];
  const int tid = threadIdx.x;
  const int wv = tid >> 6, ln = tid & 63;
  const int bid = blockIdx.x;
  const int mt = bid & 7, nt = bid >> 3;
  const int o0 = mt * 128, n0 = nt * 128;
  const int m16 = ln & 15, q4 = ln >> 4;
  const int wm = wv & 1, wn = wv >> 1;

  v4f acc[4][4];
#pragma unroll
  for (int i = 0; i < 4; i++)
#pragma unroll
    for (int j = 0; j < 4; j++) {
      v4f z = {0.f, 0.f, 0.f, 0.f};
      acc[i][j] = z;
    }

  const unsigned short* gptr[4];
  unsigned short* lptr[4];
#pragma unroll
  for (int qq = 0; qq < 4; qq++) {
    int c = wv * 4 + qq;
    int rr = (c & 7) * 16 + (ln >> 2);
    int cc = (ln & 3) * 8;
    if (c < 8) { gptr[qq] = A  + (size_t)(o0 + rr) * HH + cc; lptr[qq] = sA + c * 512; }
    else       { gptr[qq] = Bt + (size_t)(n0 + rr) * HH + cc; lptr[qq] = sB + (c - 8) * 512; }
  }

  for (int kk = 0; kk < 32; kk++) {
    const int k0 = kk * 32;
#pragma unroll
    for (int qq = 0; qq < 4; qq++) gll16(gptr[qq] + k0, lptr[qq]);
    __syncthreads();
    v8s af[4], bf4[4];
#pragma unroll
    for (int i = 0; i < 4; i++)
      af[i] = *(const v8s*)&sA[(wm * 64 + i * 16 + m16) * 32 + q4 * 8];
#pragma unroll
    for (int i = 0; i < 4; i++)
      bf4[i] = *(const v8s*)&sB[(wn * 64 + i * 16 + m16) * 32 + q4 * 8];
#pragma unroll
    for (int i = 0; i < 4; i++)
#pragma unroll
      for (int j = 0; j < 4; j++)
        acc[i][j] = __builtin_amdgcn_mfma_f32_16x16x32_bf16(af[i], bf4[j], acc[i][j], 0, 0, 0);
    __syncthreads();
  }

#pragma unroll
  for (int i = 0; i < 4; i++) {
    const int ob = o0 + wm * 64 + i * 16 + q4 * 4;
#pragma unroll
    for (int j = 0; j < 4; j++) {
      const int nn = n0 + wn * 64 + j * 16 + m16;
      const int bb = nn >> 13;
      const int l = nn & (LL - 1);
#pragma unroll
      for (int r = 0; r < 4; r++) {
        const int o = ob + r;
        out[(size_t)(bb * HH + o) * LL + l] = acc[i][j][r] + bias[o];
      }
    }
  }
}

// ---------------------------------------------------------------------------
extern "C" void kernel_launch(void* const* d_in, const int* in_sizes, int n_in,
                              void* d_out, int out_size, void* d_ws, size_t ws_size,
                              hipStream_t stream) {
  const float* u   = (const float*)d_in[0];
  const float* k0  = (const float*)d_in[1];
  const float* k1  = (const float*)d_in[2];
  const float* k2  = (const float*)d_in[3];
  const float* k3  = (const float*)d_in[4];
  const float* D   = (const float*)d_in[5];
  const float* W   = (const float*)d_in[6];
  const float* bia = (const float*)d_in[7];
  float* out = (float*)d_out;

  // ws layout: g_t (64 MiB) | k fp32 (2 MiB) | W bf16 (2 MiB)
  char* ws = (char*)d_ws;
  unsigned short* gt = (unsigned short*)ws;
  float* kws         = (float*)(ws + (size_t)67108864);
  unsigned short* Wb = (unsigned short*)(ws + (size_t)69206016);
  unsigned short* g = (unsigned short*)d_out;  // scratch in d_out

  build_k_kernel<<<HH, 512, 0, stream>>>(k0, k1, k2, k3, kws);
  w2bf_kernel<<<(HH * HH + 255) / 256, 256, 0, stream>>>(W, Wb, HH * HH);
  conv_kernel<<<2 * HH, 256, 0, stream>>>(u, kws, D, g);
  transpose_kernel<<<NB * 16 * 128, 256, 0, stream>>>(g, gt);
  gemm_kernel<<<8 * 256, 256, 0, stream>>>(Wb, gt, bia, out);
}